// Round 3
// baseline (350.457 us; speedup 1.0000x reference)
//
#include <hip/hip_runtime.h>
#include <hip/hip_bf16.h>

#define B_ 8
#define K_ 8
#define C_ 256
#define L_ 4096
#define TOPK_ 4
#define BN 128
#define LDST 40   // LDS row stride (bf16 elems): 32 data + 8 pad; 80 B rows, 16B-aligned

typedef __attribute__((ext_vector_type(8))) short bf16x8;
typedef __attribute__((ext_vector_type(4))) float f32x4;

union F4 { float4 v; float f[4]; };

__device__ __forceinline__ unsigned short f2bf(float x) {
  unsigned u = __float_as_uint(x);
  u += 0x7fffu + ((u >> 16) & 1u);   // RNE; inputs finite
  return (unsigned short)(u >> 16);
}

// top-k routing, matches jax.lax.top_k tie-break (lowest index wins via strict >)
__device__ __forceinline__ void route_b(const float* __restrict__ scores, int b,
                                        float w[TOPK_], int kk[TOPK_]) {
  float s[K_];
#pragma unroll
  for (int k = 0; k < K_; ++k) s[k] = scores[b * K_ + k];
  float sum = 0.f;
#pragma unroll
  for (int i = 0; i < TOPK_; ++i) {
    float bv = -1e30f; int bk = 0;
#pragma unroll
    for (int k = 0; k < K_; ++k)
      if (s[k] > bv) { bv = s[k]; bk = k; }
    kk[i] = bk; w[i] = bv; sum += bv;
    s[bk] = -1e30f;
  }
  float inv = 1.f / (sum + 1e-8f);
#pragma unroll
  for (int i = 0; i < TOPK_; ++i) w[i] *= inv;
}

// ---- Prepass: route + fold w into EW, stored in MFMA A-FRAGMENT order ----
// ewb layout: [blk=b*4+i][cb(8)][mi(4)][t(256)][8 bf16]
// frag (t, mi) = wi * EW[k_i][d][c..c+7], d = 64*(t>>6)+16*mi+(t&15),
//                                         c = 32*cb + 8*((t>>4)&3)
// so moe_main's A loads are direct, coalesced 16B/lane global->VGPR fragments.
__global__ __launch_bounds__(256)
void prep_kernel(const float* __restrict__ scores, const float* __restrict__ ew,
                 const float* __restrict__ eb, int* __restrict__ sel,
                 float* __restrict__ biasc, unsigned short* __restrict__ ewb) {
  const int blk = blockIdx.x;
  const int b = blk >> 2, i = blk & 3;
  const int t = threadIdx.x;
  float w[TOPK_]; int kk[TOPK_];
  route_b(scores, b, w, kk);
  if (i == 0) {
    if (t < TOPK_) sel[b * TOPK_ + t] = kk[t];
    float a = 0.f;
#pragma unroll
    for (int j = 0; j < TOPK_; ++j) a += w[j] * eb[kk[j] * C_ + t];
    biasc[b * C_ + t] = a;
  }
  const float wi = w[i];
  const float* src = ew + (size_t)kk[i] * C_ * C_;
  unsigned short* dst = ewb + (size_t)blk * 65536;
  const int dlo = t & 15, q = (t >> 4) & 3, wv = t >> 6;
#pragma unroll
  for (int cb = 0; cb < 8; ++cb) {
#pragma unroll
    for (int mi = 0; mi < 4; ++mi) {
      const int d = wv * 64 + mi * 16 + dlo;
      const float* sp = src + d * C_ + cb * 32 + q * 8;
      F4 a0, a1; a0.v = *(const float4*)sp; a1.v = *(const float4*)(sp + 4);
      union { unsigned short s[8]; bf16x8 v; } p;
#pragma unroll
      for (int e = 0; e < 4; ++e) {
        p.s[e]     = f2bf(wi * a0.f[e]);
        p.s[4 + e] = f2bf(wi * a1.f[e]);
      }
      *(bf16x8*)(dst + cb * 8192 + (mi * 256 + t) * 8) = p.v;
    }
  }
}

// ---- Main: A direct global->reg fragments (L2), B via LDS transpose ----
// Block: 256 thr (4 waves). Tile: BM=256 (all d), BN=128 (l), BK=32 (c).
// Wave w: d in [64w,64w+64) x 128 l via 4x8 of 16x16x32 bf16 MFMA.
__global__ __launch_bounds__(256, 1)
void moe_main(const float* __restrict__ xs, const unsigned short* __restrict__ ewb,
              const float* __restrict__ biasc, const int* __restrict__ sel,
              float* __restrict__ out) {
  __shared__ alignas(16) unsigned short Bs[2][BN * LDST];   // 10 KB x2

  const int t = threadIdx.x;
  const int b = blockIdx.y;
  const int l0 = blockIdx.x * BN;
  const int wave = t >> 6;
  const int lane = t & 63;
  const int l16 = lane & 15;
  const int quad = lane >> 4;
  // B staging: thread owns c in [4cg,4cg+4), l in [4lg,4lg+4)
  // (cg from low bits -> LDS writes spread over all 32 banks: 4-pass minimum)
  const int cg = t & 7;
  const int lg = t >> 3;

  int k_s[TOPK_];
#pragma unroll
  for (int i = 0; i < TOPK_; ++i) k_s[i] = sel[b * TOPK_ + i];

  f32x4 acc[4][8];
#pragma unroll
  for (int mi = 0; mi < 4; ++mi)
#pragma unroll
    for (int ni = 0; ni < 8; ++ni)
      acc[mi][ni] = (f32x4){0.f, 0.f, 0.f, 0.f};

  const unsigned short* ewb_b = ewb + (size_t)b * TOPK_ * 65536;
  bf16x8 arbuf[2][4];   // A fragments, double-buffered (never touch LDS)
  F4     brbuf[2][4];   // raw fp32 xs, double-buffered

#define ISSUE(S) do {                                                         \
    const int slot_ = (S) >> 3, cb_ = (S) & 7, pb_ = (S) & 1;                 \
    const unsigned short* ap_ = ewb_b + slot_ * 65536 + cb_ * 8192;           \
    _Pragma("unroll") for (int mi = 0; mi < 4; ++mi)                          \
      arbuf[pb_][mi] = *(const bf16x8*)(ap_ + (mi * 256 + t) * 8);            \
    const float* xp_ = xs + (((size_t)b * K_ + k_s[slot_]) * C_ +             \
                             (size_t)(cb_ * 32 + cg * 4)) * L_ + l0 + lg * 4; \
    _Pragma("unroll") for (int j = 0; j < 4; ++j)                             \
      brbuf[pb_][j].v = *(const float4*)(xp_ + (size_t)j * L_);               \
  } while (0)

  ISSUE(0);
#pragma unroll
  for (int s = 0; s < 32; ++s) {   // fully unrolled: all indices literal
    const int buf = s & 1;
    // pack B regs (fp32 -> bf16, transpose) into LDS
    unsigned short* brow = Bs[buf] + (lg * 4) * LDST + cg * 4;
#pragma unroll
    for (int i2 = 0; i2 < 4; ++i2) {
      union { __hip_bfloat162 h[2]; unsigned long long u; } pk;
      pk.h[0] = __float22bfloat162_rn(make_float2(brbuf[buf][0].f[i2], brbuf[buf][1].f[i2]));
      pk.h[1] = __float22bfloat162_rn(make_float2(brbuf[buf][2].f[i2], brbuf[buf][3].f[i2]));
      *(unsigned long long*)(brow + i2 * LDST) = pk.u;
    }
    __syncthreads();             // drains lgkm+vm; prefetch issued AFTER, so
    if (s + 1 < 32) ISSUE(s + 1); // loads get a full step before next drain
    bf16x8 bfr[8];
#pragma unroll
    for (int ni = 0; ni < 8; ++ni)
      bfr[ni] = *(const bf16x8*)(Bs[buf] + (ni * 16 + l16) * LDST + quad * 8);
#pragma unroll
    for (int mi = 0; mi < 4; ++mi)
#pragma unroll
      for (int ni = 0; ni < 8; ++ni)
        acc[mi][ni] = __builtin_amdgcn_mfma_f32_16x16x32_bf16(arbuf[buf][mi], bfr[ni], acc[mi][ni], 0, 0, 0);
  }
#undef ISSUE

  // epilogue: C/D layout col=lane&15 (l), row=quad*4+r (d)
  const float* bc = biasc + b * C_;
#pragma unroll
  for (int mi = 0; mi < 4; ++mi) {
#pragma unroll
    for (int r = 0; r < 4; ++r) {
      const int d = wave * 64 + mi * 16 + quad * 4 + r;
      const float bias = bc[d];
      float* orow = out + ((size_t)b * C_ + d) * L_ + l0;
#pragma unroll
      for (int ni = 0; ni < 8; ++ni)
        orow[ni * 16 + l16] = acc[mi][ni][r] + bias;
    }
  }
}

extern "C" void kernel_launch(void* const* d_in, const int* in_sizes, int n_in,
                              void* d_out, int out_size, void* d_ws, size_t ws_size,
                              hipStream_t stream) {
  const float* xs     = (const float*)d_in[0];
  const float* scores = (const float*)d_in[1];
  const float* ew     = (const float*)d_in[2];
  const float* eb     = (const float*)d_in[3];
  float* out = (float*)d_out;

  int*   sel   = (int*)d_ws;                                     // 32 ints
  float* biasc = (float*)((char*)d_ws + 1024);                   // 8*256 f32
  unsigned short* ewb = (unsigned short*)((char*)d_ws + 16384);  // 4 MB bf16

  prep_kernel<<<B_ * TOPK_, 256, 0, stream>>>(scores, ew, eb, sel, biasc, ewb);
  dim3 grid(L_ / BN, B_);
  moe_main<<<grid, 256, 0, stream>>>(xs, ewb, biasc, sel, out);
}